// Round 2
// baseline (1555.080 us; speedup 1.0000x reference)
//
#include <hip/hip_runtime.h>
#include <float.h>

#define D_DIM 768
#define K_DIM 500
#define KP    512
#define BM    128
#define BD    32
#define NTH   512

typedef _Float16 f16x8 __attribute__((ext_vector_type(8)));
typedef float    f32x4 __attribute__((ext_vector_type(4)));

// ---------------- cnorm prep (exact, fp64) ----------------
__global__ void cnorm_partial_kernel(const float* __restrict__ C,
                                     double* __restrict__ partial, int K) {
    const int k = threadIdx.x;
    const int w = blockIdx.x;    // 0..15
    double s = 0.0;
    if (k < K) {
        const int d0 = w * (D_DIM / 16);
        for (int d = d0; d < d0 + (D_DIM / 16); ++d) {
            const float c = C[(size_t)d * K + k];
            s = fma((double)c, (double)c, s);
        }
    }
    partial[w * 512 + k] = s;
}

__global__ void cnorm_finish_kernel(const double* __restrict__ partial,
                                    float* __restrict__ cnorm, int K) {
    const int k = threadIdx.x;
    if (k < K) {
        double s = 0.0;
        for (int w = 0; w < 16; ++w) s += partial[w * 512 + k];
        cnorm[k] = (float)s;
    } else {
        cnorm[k] = FLT_MAX;
    }
}

// ---------------- main: fp16-split MFMA GEMM + fused argmin ----------------
__launch_bounds__(NTH, 4)
__global__ void assign_kernel(const float* __restrict__ feat,
                              const float* __restrict__ Cp,
                              const float* __restrict__ cnorm,
                              int* __restrict__ out,
                              int T) {
    // LDS: A hi/lo [128][32] f16 (8KB each), B hi/lo [256][32] f16 (16KB each) = 48KB
    __shared__ __align__(16) _Float16 AsH[BM * BD];
    __shared__ __align__(16) _Float16 AsL[BM * BD];
    __shared__ __align__(16) _Float16 BsH[256 * BD];
    __shared__ __align__(16) _Float16 BsL[256 * BD];

    const int tid  = threadIdx.x;
    const int wave = tid >> 6;
    const int lane = tid & 63;
    const int wm   = wave >> 2;   // 0..1  (64-row slice)
    const int wn   = wave & 3;    // 0..3  (64-col slice per phase)
    const int l15  = lane & 15;
    const int kg   = lane >> 4;   // 0..3 (k-group)
    const int R0   = blockIdx.x * BM;

    // A staging map: 4 threads per row, 8 floats each
    const int ar = tid >> 2;            // 0..127
    const int ac = (tid & 3) << 3;      // 0,8,16,24
    const bool arow_ok = (R0 + ar) < T;
    const float* fptr = feat + (size_t)(R0 + ar) * D_DIM + ac;

    // B staging map: 256 cols x 4 dchunks, 2 chunks per thread
    const int bcol = tid & 255;
    const int bd2  = (tid >> 8) << 1;   // {0,2}

    f32x4 acc[4][8];
    #pragma unroll
    for (int m = 0; m < 4; ++m)
        #pragma unroll
        for (int n = 0; n < 8; ++n) acc[m][n] = (f32x4){0.f, 0.f, 0.f, 0.f};

#define STAGE_B(P) do {                                                        \
    _Pragma("unroll")                                                          \
    for (int c = 0; c < 2; ++c) {                                              \
        const int dch  = bd2 + c;                                              \
        const int colg = (P)*256 + bcol;                                       \
        float fb[8];                                                           \
        _Pragma("unroll")                                                      \
        for (int i = 0; i < 8; ++i)                                            \
            fb[i] = (colg < K_DIM)                                             \
                  ? Cp[(size_t)(d0 + dch*8 + i) * K_DIM + colg] : 0.0f;        \
        f16x8 h, l;                                                            \
        _Pragma("unroll")                                                      \
        for (int i = 0; i < 8; ++i) {                                          \
            const _Float16 hh = (_Float16)fb[i];                               \
            h[i] = hh; l[i] = (_Float16)(fb[i] - (float)hh);                   \
        }                                                                      \
        const int sl = (dch + (bcol >> 1)) & 3;                                \
        ((f16x8*)BsH)[bcol*4 + sl] = h;                                        \
        ((f16x8*)BsL)[bcol*4 + sl] = l;                                        \
    } } while (0)

#define MFMA_PHASE(P) do {                                                     \
    _Pragma("unroll")                                                          \
    for (int nh = 0; nh < 4; ++nh) {                                           \
        const int col = wn*64 + nh*16 + l15;                                   \
        const int sl  = (kg + (col >> 1)) & 3;                                 \
        const f16x8 bH = ((const f16x8*)BsH)[col*4 + sl];                      \
        const f16x8 bL = ((const f16x8*)BsL)[col*4 + sl];                      \
        _Pragma("unroll")                                                      \
        for (int m = 0; m < 4; ++m) {                                          \
            f32x4 a = acc[m][(P)*4 + nh];                                      \
            a = __builtin_amdgcn_mfma_f32_16x16x32_f16(aH[m], bH, a, 0, 0, 0); \
            a = __builtin_amdgcn_mfma_f32_16x16x32_f16(aL[m], bH, a, 0, 0, 0); \
            a = __builtin_amdgcn_mfma_f32_16x16x32_f16(aH[m], bL, a, 0, 0, 0); \
            acc[m][(P)*4 + nh] = a;                                            \
        }                                                                      \
    } } while (0)

    for (int d0 = 0; d0 < D_DIM; d0 += BD) {
        // ---- stage A (fp32 -> f16 hi/lo) + B phase 0
        {
            float4 v0 = make_float4(0.f,0.f,0.f,0.f), v1 = v0;
            if (arow_ok) {
                v0 = *(const float4*)(fptr + d0);
                v1 = *(const float4*)(fptr + d0 + 4);
            }
            const float fa[8] = {v0.x, v0.y, v0.z, v0.w, v1.x, v1.y, v1.z, v1.w};
            f16x8 h, l;
            #pragma unroll
            for (int j = 0; j < 8; ++j) {
                const _Float16 hh = (_Float16)fa[j];
                h[j] = hh; l[j] = (_Float16)(fa[j] - (float)hh);
            }
            const int sl = ((ac >> 3) + (ar >> 1)) & 3;
            ((f16x8*)AsH)[ar*4 + sl] = h;
            ((f16x8*)AsL)[ar*4 + sl] = l;
        }
        STAGE_B(0);
        __syncthreads();

        // ---- A fragments (held across both phases)
        f16x8 aH[4], aL[4];
        #pragma unroll
        for (int m = 0; m < 4; ++m) {
            const int row = wm*64 + m*16 + l15;
            const int sl  = (kg + (row >> 1)) & 3;
            aH[m] = ((const f16x8*)AsH)[row*4 + sl];
            aL[m] = ((const f16x8*)AsL)[row*4 + sl];
        }
        MFMA_PHASE(0);
        __syncthreads();

        STAGE_B(1);
        __syncthreads();
        MFMA_PHASE(1);
        __syncthreads();
    }

    // ---------------- epilogue: fused argmin ----------------
    float cn[8];
    #pragma unroll
    for (int n = 0; n < 8; ++n) {
        const int colg = (n >> 2)*256 + wn*64 + (n & 3)*16 + l15;
        cn[n] = cnorm[colg];
    }

    float* red_v = (float*)AsH;   // [128][4]
    int*   red_i = (int*)AsL;     // [128][4]

    #pragma unroll
    for (int m = 0; m < 4; ++m) {
        #pragma unroll
        for (int r = 0; r < 4; ++r) {
            float best = cn[0] - 2.0f * acc[m][0][r];
            int   bi   = wn*64 + l15;
            #pragma unroll
            for (int n = 1; n < 8; ++n) {
                const int col = (n >> 2)*256 + wn*64 + (n & 3)*16 + l15;
                const float s = cn[n] - 2.0f * acc[m][n][r];
                if (s < best || (s == best && col < bi)) { best = s; bi = col; }
            }
            #pragma unroll
            for (int msk = 1; msk < 16; msk <<= 1) {
                const float ov = __shfl_xor(best, msk, 64);
                const int   oi = __shfl_xor(bi,   msk, 64);
                if (ov < best || (ov == best && oi < bi)) { best = ov; bi = oi; }
            }
            if (l15 == 0) {
                const int rl = wm*64 + m*16 + kg*4 + r;
                red_v[rl*4 + wn] = best;
                red_i[rl*4 + wn] = bi;
            }
        }
    }
    __syncthreads();

    if (tid < BM) {
        float bv = red_v[tid*4];
        int   bi = red_i[tid*4];
        #pragma unroll
        for (int w = 1; w < 4; ++w) {
            const float v = red_v[tid*4 + w];
            const int   i = red_i[tid*4 + w];
            if (v < bv || (v == bv && i < bi)) { bv = v; bi = i; }
        }
        const int r = R0 + tid;
        if (r < T) out[r] = bi;
    }
#undef STAGE_B
#undef MFMA_PHASE
}

extern "C" void kernel_launch(void* const* d_in, const int* in_sizes, int n_in,
                              void* d_out, int out_size, void* d_ws, size_t ws_size,
                              hipStream_t stream) {
    const float* feat = (const float*)d_in[0];
    const float* C    = (const float*)d_in[1];
    int* out          = (int*)d_out;
    const int T = in_sizes[0] / D_DIM;   // 100000
    const int K = in_sizes[1] / D_DIM;   // 500

    float*  cnorm   = (float*)d_ws;
    double* partial = (double*)((char*)d_ws + 4096);

    hipLaunchKernelGGL(cnorm_partial_kernel, dim3(16), dim3(512), 0, stream,
                       C, partial, K);
    hipLaunchKernelGGL(cnorm_finish_kernel, dim3(1), dim3(512), 0, stream,
                       partial, cnorm, K);

    const int grid = (T + BM - 1) / BM;
    hipLaunchKernelGGL(assign_kernel, dim3(grid), dim3(NTH), 0, stream,
                       feat, C, cnorm, out, T);
}

// Round 3
// 416.583 us; speedup vs baseline: 3.7329x; 3.7329x over previous
//
#include <hip/hip_runtime.h>
#include <float.h>

#define D_DIM 768
#define K_DIM 500
#define KP    512
#define BM    128
#define BD    32
#define NTH   512

typedef _Float16 f16x8 __attribute__((ext_vector_type(8)));
typedef float    f32x4 __attribute__((ext_vector_type(4)));

// ---------------- cnorm prep (exact, fp64) ----------------
__global__ void cnorm_partial_kernel(const float* __restrict__ C,
                                     double* __restrict__ partial, int K) {
    const int k = threadIdx.x;
    const int w = blockIdx.x;    // 0..15
    double s = 0.0;
    if (k < K) {
        const int d0 = w * (D_DIM / 16);
        for (int d = d0; d < d0 + (D_DIM / 16); ++d) {
            const float c = C[(size_t)d * K + k];
            s = fma((double)c, (double)c, s);
        }
    }
    partial[w * 512 + k] = s;
}

__global__ void cnorm_finish_kernel(const double* __restrict__ partial,
                                    float* __restrict__ cnorm, int K) {
    const int k = threadIdx.x;
    if (k < K) {
        double s = 0.0;
        for (int w = 0; w < 16; ++w) s += partial[w * 512 + k];
        cnorm[k] = (float)s;
    } else {
        cnorm[k] = FLT_MAX;
    }
}

// ---------------- main: fp16-split MFMA GEMM + fused argmin ----------------
__launch_bounds__(NTH, 2)
__global__ void assign_kernel(const float* __restrict__ feat,
                              const float* __restrict__ Cp,
                              const float* __restrict__ cnorm,
                              int* __restrict__ out,
                              int T) {
    // LDS: A hi/lo [128][32] f16 (8KB each), B hi/lo [256][32] f16 (16KB each) = 48KB
    __shared__ __align__(16) _Float16 AsH[BM * BD];
    __shared__ __align__(16) _Float16 AsL[BM * BD];
    __shared__ __align__(16) _Float16 BsH[256 * BD];
    __shared__ __align__(16) _Float16 BsL[256 * BD];

    const int tid  = threadIdx.x;
    const int wave = tid >> 6;
    const int lane = tid & 63;
    const int wm   = wave >> 2;   // 0..1  (64-row slice)
    const int wn   = wave & 3;    // 0..3  (64-col slice per phase)
    const int l15  = lane & 15;
    const int kg   = lane >> 4;   // 0..3 (k-group)
    const int R0   = blockIdx.x * BM;

    // A staging map: 4 threads per row, 8 floats each
    const int ar = tid >> 2;            // 0..127
    const int ac = (tid & 3) << 3;      // 0,8,16,24
    const bool arow_ok = (R0 + ar) < T;
    const float* fptr = feat + (size_t)(R0 + ar) * D_DIM + ac;

    // B staging map: 256 cols x 4 dchunks, 2 chunks per thread
    const int bcol = tid & 255;
    const int bd2  = (tid >> 8) << 1;   // {0,2}

    f32x4 acc[4][8];
    #pragma unroll
    for (int m = 0; m < 4; ++m)
        #pragma unroll
        for (int n = 0; n < 8; ++n) acc[m][n] = (f32x4){0.f, 0.f, 0.f, 0.f};

#define STAGE_B(P) do {                                                        \
    _Pragma("unroll")                                                          \
    for (int c = 0; c < 2; ++c) {                                              \
        const int dch  = bd2 + c;                                              \
        const int colg = (P)*256 + bcol;                                       \
        float fb[8];                                                           \
        _Pragma("unroll")                                                      \
        for (int i = 0; i < 8; ++i)                                            \
            fb[i] = (colg < K_DIM)                                             \
                  ? Cp[(size_t)(d0 + dch*8 + i) * K_DIM + colg] : 0.0f;        \
        f16x8 h, l;                                                            \
        _Pragma("unroll")                                                      \
        for (int i = 0; i < 8; ++i) {                                          \
            const _Float16 hh = (_Float16)fb[i];                               \
            h[i] = hh; l[i] = (_Float16)(fb[i] - (float)hh);                   \
        }                                                                      \
        const int sl = (dch + (bcol >> 1)) & 3;                                \
        ((f16x8*)BsH)[bcol*4 + sl] = h;                                        \
        ((f16x8*)BsL)[bcol*4 + sl] = l;                                        \
    } } while (0)

#define MFMA_PHASE(P) do {                                                     \
    _Pragma("unroll")                                                          \
    for (int nh = 0; nh < 4; ++nh) {                                           \
        const int col = wn*64 + nh*16 + l15;                                   \
        const int sl  = (kg + (col >> 1)) & 3;                                 \
        const f16x8 bH = ((const f16x8*)BsH)[col*4 + sl];                      \
        const f16x8 bL = ((const f16x8*)BsL)[col*4 + sl];                      \
        _Pragma("unroll")                                                      \
        for (int m = 0; m < 4; ++m) {                                          \
            f32x4 a = acc[m][(P)*4 + nh];                                      \
            a = __builtin_amdgcn_mfma_f32_16x16x32_f16(aH[m], bH, a, 0, 0, 0); \
            a = __builtin_amdgcn_mfma_f32_16x16x32_f16(aL[m], bH, a, 0, 0, 0); \
            a = __builtin_amdgcn_mfma_f32_16x16x32_f16(aH[m], bL, a, 0, 0, 0); \
            acc[m][(P)*4 + nh] = a;                                            \
        }                                                                      \
    } } while (0)

    for (int d0 = 0; d0 < D_DIM; d0 += BD) {
        // ---- stage A (fp32 -> f16 hi/lo) + B phase 0
        {
            float4 v0 = make_float4(0.f,0.f,0.f,0.f), v1 = v0;
            if (arow_ok) {
                v0 = *(const float4*)(fptr + d0);
                v1 = *(const float4*)(fptr + d0 + 4);
            }
            const float fa[8] = {v0.x, v0.y, v0.z, v0.w, v1.x, v1.y, v1.z, v1.w};
            f16x8 h, l;
            #pragma unroll
            for (int j = 0; j < 8; ++j) {
                const _Float16 hh = (_Float16)fa[j];
                h[j] = hh; l[j] = (_Float16)(fa[j] - (float)hh);
            }
            const int sl = ((ac >> 3) + (ar >> 1)) & 3;
            ((f16x8*)AsH)[ar*4 + sl] = h;
            ((f16x8*)AsL)[ar*4 + sl] = l;
        }
        STAGE_B(0);
        __syncthreads();

        // ---- A fragments (held across both phases)
        f16x8 aH[4], aL[4];
        #pragma unroll
        for (int m = 0; m < 4; ++m) {
            const int row = wm*64 + m*16 + l15;
            const int sl  = (kg + (row >> 1)) & 3;
            aH[m] = ((const f16x8*)AsH)[row*4 + sl];
            aL[m] = ((const f16x8*)AsL)[row*4 + sl];
        }
        MFMA_PHASE(0);
        __syncthreads();

        STAGE_B(1);
        __syncthreads();
        MFMA_PHASE(1);
        __syncthreads();
    }

    // ---------------- epilogue: fused argmin ----------------
    float cn[8];
    #pragma unroll
    for (int n = 0; n < 8; ++n) {
        const int colg = (n >> 2)*256 + wn*64 + (n & 3)*16 + l15;
        cn[n] = cnorm[colg];
    }

    float* red_v = (float*)AsH;   // [128][4]
    int*   red_i = (int*)AsL;     // [128][4]

    #pragma unroll
    for (int m = 0; m < 4; ++m) {
        #pragma unroll
        for (int r = 0; r < 4; ++r) {
            float best = cn[0] - 2.0f * acc[m][0][r];
            int   bi   = wn*64 + l15;
            #pragma unroll
            for (int n = 1; n < 8; ++n) {
                const int col = (n >> 2)*256 + wn*64 + (n & 3)*16 + l15;
                const float s = cn[n] - 2.0f * acc[m][n][r];
                if (s < best || (s == best && col < bi)) { best = s; bi = col; }
            }
            #pragma unroll
            for (int msk = 1; msk < 16; msk <<= 1) {
                const float ov = __shfl_xor(best, msk, 64);
                const int   oi = __shfl_xor(bi,   msk, 64);
                if (ov < best || (ov == best && oi < bi)) { best = ov; bi = oi; }
            }
            if (l15 == 0) {
                const int rl = wm*64 + m*16 + kg*4 + r;
                red_v[rl*4 + wn] = best;
                red_i[rl*4 + wn] = bi;
            }
        }
    }
    __syncthreads();

    if (tid < BM) {
        float bv = red_v[tid*4];
        int   bi = red_i[tid*4];
        #pragma unroll
        for (int w = 1; w < 4; ++w) {
            const float v = red_v[tid*4 + w];
            const int   i = red_i[tid*4 + w];
            if (v < bv || (v == bv && i < bi)) { bv = v; bi = i; }
        }
        const int r = R0 + tid;
        if (r < T) out[r] = bi;
    }
#undef STAGE_B
#undef MFMA_PHASE
}

extern "C" void kernel_launch(void* const* d_in, const int* in_sizes, int n_in,
                              void* d_out, int out_size, void* d_ws, size_t ws_size,
                              hipStream_t stream) {
    const float* feat = (const float*)d_in[0];
    const float* C    = (const float*)d_in[1];
    int* out          = (int*)d_out;
    const int T = in_sizes[0] / D_DIM;   // 100000
    const int K = in_sizes[1] / D_DIM;   // 500

    float*  cnorm   = (float*)d_ws;
    double* partial = (double*)((char*)d_ws + 4096);

    hipLaunchKernelGGL(cnorm_partial_kernel, dim3(16), dim3(512), 0, stream,
                       C, partial, K);
    hipLaunchKernelGGL(cnorm_finish_kernel, dim3(1), dim3(512), 0, stream,
                       partial, cnorm, K);

    const int grid = (T + BM - 1) / BM;
    hipLaunchKernelGGL(assign_kernel, dim3(grid), dim3(NTH), 0, stream,
                       feat, C, cnorm, out, T);
}

// Round 4
// 351.087 us; speedup vs baseline: 4.4293x; 1.1866x over previous
//
#include <hip/hip_runtime.h>
#include <float.h>

#define D_DIM 768
#define K_DIM 500
#define NDT   24          // 768 / 32 D-tiles
#define BM    128
#define BD    32
#define NTH   512

typedef _Float16 f16x8 __attribute__((ext_vector_type(8)));
typedef float    f32x4 __attribute__((ext_vector_type(4)));

// ws layout:
//   0        : cnorm   float[512]                 (2 KB)
//   4096     : partial double[16*512]             (64 KB)
//   131072   : BpH     _Float16[24*512*32]        (768 KB)
//   917504   : BpL     _Float16[24*512*32]        (768 KB)

// ---------------- cnorm prep (exact, fp64) ----------------
__global__ void cnorm_partial_kernel(const float* __restrict__ C,
                                     double* __restrict__ partial, int K) {
    const int k = threadIdx.x;
    const int w = blockIdx.x;    // 0..15
    double s = 0.0;
    if (k < K) {
        const int d0 = w * (D_DIM / 16);
        for (int d = d0; d < d0 + (D_DIM / 16); ++d) {
            const float c = C[(size_t)d * K + k];
            s = fma((double)c, (double)c, s);
        }
    }
    partial[w * 512 + k] = s;
}

__global__ void cnorm_finish_kernel(const double* __restrict__ partial,
                                    float* __restrict__ cnorm, int K) {
    const int k = threadIdx.x;
    if (k < K) {
        double s = 0.0;
        for (int w = 0; w < 16; ++w) s += partial[w * 512 + k];
        cnorm[k] = (float)s;
    } else {
        cnorm[k] = FLT_MAX;
    }
}

// ---------------- pack C into fragment-ready f16 hi/lo planes ----------------
// Bp[dt][col][k]: for D-tile dt, column col (0..511, zero-padded), 32 k-values
// contiguous. Lane kg reads k = kg*8..kg*8+7 as one 16B chunk.
__global__ void packB_kernel(const float* __restrict__ C,
                             _Float16* __restrict__ BpH,
                             _Float16* __restrict__ BpL) {
    const int idx = blockIdx.x * 256 + threadIdx.x;   // 0..12287
    const int col = idx & 511;
    const int dt  = idx >> 9;                         // 0..23
    f16x8 h[4], l[4];
    #pragma unroll
    for (int c = 0; c < 4; ++c)
        #pragma unroll
        for (int j = 0; j < 8; ++j) {
            const int k = c * 8 + j;
            const float v = (col < K_DIM)
                          ? C[(size_t)(dt * 32 + k) * K_DIM + col] : 0.0f;
            const _Float16 hh = (_Float16)v;
            h[c][j] = hh;
            l[c][j] = (_Float16)(v - (float)hh);
        }
    f16x8* dH = (f16x8*)(BpH + ((size_t)dt * 512 + col) * 32);
    f16x8* dL = (f16x8*)(BpL + ((size_t)dt * 512 + col) * 32);
    #pragma unroll
    for (int c = 0; c < 4; ++c) { dH[c] = h[c]; dL[c] = l[c]; }
}

// ---------------- main: fp16-split MFMA + direct-global B + fused argmin ----
__launch_bounds__(NTH, 2)
__global__ void assign_kernel(const float* __restrict__ feat,
                              const _Float16* __restrict__ BpH,
                              const _Float16* __restrict__ BpL,
                              const float* __restrict__ cnorm,
                              int* __restrict__ out,
                              int T) {
    // A tiles only, double-buffered: 2 planes x 2 bufs x 8KB = 32KB
    __shared__ __align__(16) _Float16 AsH[2][BM * BD];
    __shared__ __align__(16) _Float16 AsL[2][BM * BD];

    const int tid  = threadIdx.x;
    const int wave = tid >> 6;
    const int lane = tid & 63;
    const int wm   = wave >> 2;   // 0..1  (64-row slice)
    const int wn   = wave & 3;    // 0..3  (64-col slice per 256-col half)
    const int l15  = lane & 15;
    const int kg   = lane >> 4;   // 0..3  (k-group)
    const int R0   = blockIdx.x * BM;

    // A staging map: 4 threads per row, 8 floats each
    const int ar = tid >> 2;            // 0..127
    const int ac = (tid & 3) << 3;      // 0,8,16,24
    const bool arow_ok = (R0 + ar) < T;
    const float* fptr = feat + (size_t)(R0 + ar) * D_DIM + ac;
    const int asl = ((ac >> 3) + (ar >> 1)) & 3;      // slot swizzle for write

    // B fragment base (element index) for this wave: col = wn*64 + l15
    const int colbase = wn * 64 + l15;

    f32x4 acc[4][8];
    #pragma unroll
    for (int m = 0; m < 4; ++m)
        #pragma unroll
        for (int n = 0; n < 8; ++n) acc[m][n] = (f32x4){0.f, 0.f, 0.f, 0.f};

    // ---- prologue: stage A tile for dt = 0
    {
        float4 v0 = make_float4(0.f, 0.f, 0.f, 0.f), v1 = v0;
        if (arow_ok) {
            v0 = *(const float4*)(fptr);
            v1 = *(const float4*)(fptr + 4);
        }
        const float fa[8] = {v0.x, v0.y, v0.z, v0.w, v1.x, v1.y, v1.z, v1.w};
        f16x8 h, l;
        #pragma unroll
        for (int j = 0; j < 8; ++j) {
            const _Float16 hh = (_Float16)fa[j];
            h[j] = hh; l[j] = (_Float16)(fa[j] - (float)hh);
        }
        ((f16x8*)AsH[0])[ar * 4 + asl] = h;
        ((f16x8*)AsL[0])[ar * 4 + asl] = l;
    }
    __syncthreads();

    for (int dt = 0; dt < NDT; ++dt) {
        const int cur = dt & 1;
        const bool hasNext = (dt + 1) < NDT;

        // ---- issue next A-tile global loads (latency hidden under MFMAs)
        float4 v0 = make_float4(0.f, 0.f, 0.f, 0.f), v1 = v0;
        if (hasNext && arow_ok) {
            v0 = *(const float4*)(fptr + (dt + 1) * BD);
            v1 = *(const float4*)(fptr + (dt + 1) * BD + 4);
        }

        // ---- A fragments from LDS buf[cur]
        f16x8 aH[4], aL[4];
        #pragma unroll
        for (int m = 0; m < 4; ++m) {
            const int row = wm * 64 + m * 16 + l15;
            const int sl  = (kg + (row >> 1)) & 3;
            aH[m] = ((const f16x8*)AsH[cur])[row * 4 + sl];
            aL[m] = ((const f16x8*)AsL[cur])[row * 4 + sl];
        }

        // ---- B fragments direct from L2-resident packed planes + MFMA
        const size_t bbase = ((size_t)dt * 512 + colbase) * 32 + kg * 8;
        #pragma unroll
        for (int half = 0; half < 2; ++half) {
            const size_t hb = bbase + (size_t)half * 256 * 32;
            f16x8 bH[4], bL[4];
            #pragma unroll
            for (int nh = 0; nh < 4; ++nh) {
                bH[nh] = *(const f16x8*)(BpH + hb + nh * 16 * 32);
                bL[nh] = *(const f16x8*)(BpL + hb + nh * 16 * 32);
            }
            #pragma unroll
            for (int nh = 0; nh < 4; ++nh) {
                #pragma unroll
                for (int m = 0; m < 4; ++m) {
                    f32x4 a = acc[m][half * 4 + nh];
                    a = __builtin_amdgcn_mfma_f32_16x16x32_f16(aH[m], bH[nh], a, 0, 0, 0);
                    a = __builtin_amdgcn_mfma_f32_16x16x32_f16(aL[m], bH[nh], a, 0, 0, 0);
                    a = __builtin_amdgcn_mfma_f32_16x16x32_f16(aH[m], bL[nh], a, 0, 0, 0);
                    acc[m][half * 4 + nh] = a;
                }
            }
        }

        // ---- convert + stage next A tile into buf[cur^1]
        if (hasNext) {
            const float fa[8] = {v0.x, v0.y, v0.z, v0.w, v1.x, v1.y, v1.z, v1.w};
            f16x8 h, l;
            #pragma unroll
            for (int j = 0; j < 8; ++j) {
                const _Float16 hh = (_Float16)fa[j];
                h[j] = hh; l[j] = (_Float16)(fa[j] - (float)hh);
            }
            ((f16x8*)AsH[cur ^ 1])[ar * 4 + asl] = h;
            ((f16x8*)AsL[cur ^ 1])[ar * 4 + asl] = l;
        }
        __syncthreads();
    }

    // ---------------- epilogue: fused argmin ----------------
    float cn[8];
    #pragma unroll
    for (int n = 0; n < 8; ++n) {
        const int colg = (n >> 2) * 256 + wn * 64 + (n & 3) * 16 + l15;
        cn[n] = cnorm[colg];
    }

    float* red_v = (float*)AsH;   // [128][4]
    int*   red_i = (int*)AsL;     // [128][4]

    #pragma unroll
    for (int m = 0; m < 4; ++m) {
        #pragma unroll
        for (int r = 0; r < 4; ++r) {
            float best = cn[0] - 2.0f * acc[m][0][r];
            int   bi   = wn * 64 + l15;
            #pragma unroll
            for (int n = 1; n < 8; ++n) {
                const int col = (n >> 2) * 256 + wn * 64 + (n & 3) * 16 + l15;
                const float s = cn[n] - 2.0f * acc[m][n][r];
                if (s < best || (s == best && col < bi)) { best = s; bi = col; }
            }
            #pragma unroll
            for (int msk = 1; msk < 16; msk <<= 1) {
                const float ov = __shfl_xor(best, msk, 64);
                const int   oi = __shfl_xor(bi,   msk, 64);
                if (ov < best || (ov == best && oi < bi)) { best = ov; bi = oi; }
            }
            if (l15 == 0) {
                const int rl = wm * 64 + m * 16 + kg * 4 + r;
                red_v[rl * 4 + wn] = best;
                red_i[rl * 4 + wn] = bi;
            }
        }
    }
    __syncthreads();

    if (tid < BM) {
        float bv = red_v[tid * 4];
        int   bi = red_i[tid * 4];
        #pragma unroll
        for (int w = 1; w < 4; ++w) {
            const float v = red_v[tid * 4 + w];
            const int   i = red_i[tid * 4 + w];
            if (v < bv || (v == bv && i < bi)) { bv = v; bi = i; }
        }
        const int r = R0 + tid;
        if (r < T) out[r] = bi;
    }
}

extern "C" void kernel_launch(void* const* d_in, const int* in_sizes, int n_in,
                              void* d_out, int out_size, void* d_ws, size_t ws_size,
                              hipStream_t stream) {
    const float* feat = (const float*)d_in[0];
    const float* C    = (const float*)d_in[1];
    int* out          = (int*)d_out;
    const int T = in_sizes[0] / D_DIM;   // 100000
    const int K = in_sizes[1] / D_DIM;   // 500

    float*     cnorm   = (float*)d_ws;
    double*    partial = (double*)((char*)d_ws + 4096);
    _Float16*  BpH     = (_Float16*)((char*)d_ws + 131072);
    _Float16*  BpL     = (_Float16*)((char*)d_ws + 917504);

    hipLaunchKernelGGL(cnorm_partial_kernel, dim3(16), dim3(512), 0, stream,
                       C, partial, K);
    hipLaunchKernelGGL(cnorm_finish_kernel, dim3(1), dim3(512), 0, stream,
                       partial, cnorm, K);
    hipLaunchKernelGGL(packB_kernel, dim3(48), dim3(256), 0, stream,
                       C, BpH, BpL);

    const int grid = (T + BM - 1) / BM;
    hipLaunchKernelGGL(assign_kernel, dim3(grid), dim3(NTH), 0, stream,
                       feat, BpH, BpL, cnorm, out, T);
}